// Round 10
// baseline (139.436 us; speedup 1.0000x reference)
//
#include <hip/hip_runtime.h>
#include <math.h>

#define Bz 8
#define Cc 12
#define Ss 784
#define Nn 785
#define Dd 768
#define Hh 28
#define K1 512
#define PATCHNUM 84

#define NPROD 96                  // one block per (b,c)
#define NG1 96                    // 8b * 12 colblocks
#define NG2 16                    // 8b * 2 halves
#define NNODE1 (NPROD + NG1 + NG2) // 208
#define NCPY 4704                 // 8*784*768/4 / 256 exactly

#define MAGIC 0x5EC7ED42C0FFEE01ULL

__device__ inline float waveSum(float v) {
#pragma unroll
    for (int off = 32; off > 0; off >>= 1) v += __shfl_xor(v, off);
    return v;
}

struct GT { float sc[Ss]; };
struct G1 {
    float m[Ss];
    float pw[Ss];
    float g[K1];
    float part[4][64];
    float w4[4][4];
    float av[4];
    int   ai4[4];
};
struct G2 {
    int cnt[Ss];
    int cc[Ss];
    int found[64];
};
union SMem { GT gt; G1 g1; G2 g2; };

// ---------------- Node 1: 96 topk producers + 112 consumers, cheap flag sync ----------------
__global__ __launch_bounds__(256) void kNode1(const float* __restrict__ hs,
                                              const float* __restrict__ x,
                                              const float* __restrict__ w1,
                                              const float* __restrict__ w2,
                                              float* __restrict__ nscore,
                                              unsigned char* __restrict__ flags,
                                              unsigned long long* __restrict__ ready,
                                              float* __restrict__ out,
                                              int select_num) {
    __shared__ SMem sm;
    int bid = blockIdx.x;
    int tid = threadIdx.x;
    int lane = tid & 63, wid = tid >> 6;

    if (bid < NPROD) {
        // ======== producer: per (b,c) top-84 rank (4 values/thread) ========
        int bc = bid;
        const float* sc = x + (size_t)bc * Nn * Nn + 1;   // x[b,c,0,1:]
        float* s_sc = sm.gt.sc;
        for (int s = tid; s < Ss; s += 256) s_sc[s] = sc[s];
        __syncthreads();

        float v[4]; int rank[4];
#pragma unroll
        for (int q = 0; q < 4; ++q) {
            int s = tid + 256 * q;
            v[q] = (s < Ss) ? s_sc[s] : 0.f;
            rank[q] = 0;
        }
        const float4* s4 = (const float4*)s_sc;
        for (int ch = 0; ch < 49; ++ch) {                 // 49 chunks of 16
            float4 c0 = s4[ch * 4 + 0];
            float4 c1 = s4[ch * 4 + 1];
            float4 c2 = s4[ch * 4 + 2];
            float4 c3 = s4[ch * 4 + 3];
            float c[16] = {c0.x, c0.y, c0.z, c0.w, c1.x, c1.y, c1.z, c1.w,
                           c2.x, c2.y, c2.z, c2.w, c3.x, c3.y, c3.z, c3.w};
#pragma unroll
            for (int u = 0; u < 16; ++u) {
                int t = ch * 16 + u;
#pragma unroll
                for (int q = 0; q < 4; ++q)
                    rank[q] += (c[u] > v[q]) || (c[u] == v[q] && t < tid + 256 * q);
            }
        }
#pragma unroll
        for (int q = 0; q < 4; ++q) {
            int s = tid + 256 * q;
            if (s < Ss) {
                bool sel = rank[q] < PATCHNUM;            // lax.top_k tie-break: lower index
                flags[(size_t)bc * Ss + s] = sel ? 1 : 0;
                nscore[(size_t)bc * Ss + s] = sel ? v[q] : v[q] * 0.7f;
            }
        }
        __syncthreads();                                  // all stores issued
        if (tid == 0) {
            __threadfence();                              // release: wb dirty L2 to coherent point
            atomicExch(&ready[bc], (unsigned long long)MAGIC);
        }
    } else {
        // ======== consumers: wait only for the 12 producers of my b ========
        int b;
        if (bid < NPROD + NG1) b = (bid - NPROD) / 12;
        else                   b = (bid - NPROD - NG1) >> 1;

        if (tid < 12) {
            // plain coherent load, no RMW: no L2 atomic-pipe serialization
            while (__hip_atomic_load(&ready[b * 12 + tid], __ATOMIC_RELAXED,
                                     __HIP_MEMORY_SCOPE_AGENT) != MAGIC)
                __builtin_amdgcn_s_sleep(2);
        }
        __syncthreads();
        __threadfence();                                  // acquire: invalidate stale lines

        if (bid < NPROD + NG1) {
            // ---- group 1: per-b stats + 64-col slice of o2; write out row 0 ----
            G1& S = sm.g1;
            int u0 = bid - NPROD;
            int colblk = u0 % 12;

            // phase 1: m, pw, sum(m), P2p, P2n
            const float* ns = nscore + (size_t)b * Cc * Ss;
            float lsum = 0.f, lp = 0.f, ln2 = 0.f;
            for (int s = tid; s < Ss; s += 256) {
                float m = 0.f;
#pragma unroll
                for (int c = 0; c < Cc; ++c) m += ns[c * Ss + s];
                S.m[s] = m;
                float pw = m / 12.0f;
                S.pw[s] = pw;
                lsum += m;
                if (pw > 0.f) lp += pw * pw;
                else if (pw < 0.f) ln2 += pw * pw;
            }
            lsum = waveSum(lsum); lp = waveSum(lp); ln2 = waveSum(ln2);
            if (lane == 0) {
                S.w4[wid][0] = lsum; S.w4[wid][1] = lp; S.w4[wid][2] = ln2;
            }
            __syncthreads();
            float meanm = (S.w4[0][0] + S.w4[1][0] + S.w4[2][0] + S.w4[3][0]) / 784.0f;
            float P2p   =  S.w4[0][1] + S.w4[1][1] + S.w4[2][1] + S.w4[3][1];
            float P2n   =  S.w4[0][2] + S.w4[1][2] + S.w4[2][2] + S.w4[3][2];

            // phase 2: anchor = argmax_s ((m>mean) ? pw : 0), first max wins
            float bv = -INFINITY; int bi = Ss;
            for (int s = tid; s < Ss; s += 256) {
                float z = (S.m[s] > meanm) ? S.pw[s] : 0.0f;
                if (z > bv) { bv = z; bi = s; }
            }
#pragma unroll
            for (int off = 32; off > 0; off >>= 1) {
                float ov = __shfl_xor(bv, off);
                int   oi = __shfl_xor(bi, off);
                if (ov > bv || (ov == bv && oi < bi)) { bv = ov; bi = oi; }
            }
            if (lane == 0) { S.av[wid] = bv; S.ai4[wid] = bi; }
            __syncthreads();
            float abv = S.av[0]; int anchor = S.ai4[0];
#pragma unroll
            for (int w = 1; w < 4; ++w) {
                if (S.av[w] > abv || (S.av[w] == abv && S.ai4[w] < anchor)) {
                    abv = S.av[w]; anchor = S.ai4[w];
                }
            }

            // phase 3: A, G (depend on anchor)
            int ai = anchor / Hh, aj = anchor % Hh;
            float lA = 0.f, lG = 0.f;
            const float PI_F = 3.14159265358979323846f;
            for (int s = tid; s < Ss; s += 256) {
                float pw = S.pw[s];
                int i = s / Hh, j = s % Hh;
                float ri = (float)(i - ai) / 28.0f;
                float rj = (float)(j - aj) / 28.0f;
                float dist = sqrtf(ri * ri + rj * rj);
                float ang = (atan2f(rj, ri) / PI_F + 1.0f) * 0.5f;
                lA += pw * dist;
                lG += pw * ang;
            }
            lA = waveSum(lA); lG = waveSum(lG);
            __syncthreads();
            if (lane == 0) { S.w4[wid][0] = lA; S.w4[wid][1] = lG; }
            __syncthreads();
            float A = S.w4[0][0] + S.w4[1][0] + S.w4[2][0] + S.w4[3][0];
            float G = S.w4[0][1] + S.w4[1][1] + S.w4[2][1] + S.w4[3][1];
            float pwA = S.pw[anchor];
            float cp = pwA * P2p, cn = pwA * P2n;

            // phase 4: g[k]
            for (int k = tid; k < K1; k += 256) {
                float v = A * w1[k] + G * w1[K1 + k];
                S.g[k] = cp * fmaxf(v, 0.f) - cn * fmaxf(-v, 0.f);
            }
            __syncthreads();

            // phase 5: matvec 64 cols, 4 k-chunks
            int col = colblk * 64 + lane;
            int kc = wid;                          // 0..3, 128 k each
            float acc = 0.f;
            const float* w2p = w2 + (size_t)(kc * 128) * Dd + col;
#pragma unroll 8
            for (int kk = 0; kk < 128; ++kk)
                acc += S.g[kc * 128 + kk] * w2p[kk * Dd];
            S.part[kc][lane] = acc;
            __syncthreads();
            if (tid < 64) {
                float o2 = S.part[0][tid] + S.part[1][tid] + S.part[2][tid] + S.part[3][tid];
                float r = (o2 > 0.f) ? o2 : 0.2f * o2;
                size_t off = (size_t)b * Nn * Dd + colblk * 64 + tid;   // row 0
                out[off] = hs[off] + r;
            }
        } else {
            // ---- group 2: count -> conv -> stable rank -> gather rows ----
            G2& S = sm.g2;
            int u = bid - (NPROD + NG1);
            int half = u & 1;

            for (int r = tid; r < 64; r += 256) S.found[r] = -1;
            for (int s = tid; s < Ss; s += 256) {
                int c0 = 0;
#pragma unroll
                for (int c = 0; c < Cc; ++c) c0 += flags[((size_t)b * Cc + c) * Ss + s];
                S.cnt[s] = c0;
            }
            __syncthreads();
            for (int s = tid; s < Ss; s += 256) {
                int i = s / Hh, j = s % Hh;
                int acc = 0;
                for (int di = -1; di <= 1; ++di)
                    for (int dj = -1; dj <= 1; ++dj) {
                        int ii = i + di, jj = j + dj;
                        if (ii >= 0 && ii < Hh && jj >= 0 && jj < Hh)
                            acc += ((di == 0) ? 2 : 1) * ((dj == 0) ? 2 : 1) * S.cnt[ii * Hh + jj];
                    }
                S.cc[s] = acc;
            }
            __syncthreads();

            int sA = half * 392 + tid;                       // [h*392, h*392+256)
            int sB = (tid < 136) ? (half * 392 + 256 + tid) : -1;
            int vA = S.cc[sA];
            int vB = (sB >= 0) ? S.cc[sB] : 0;
            int rA = 0, rB = 0;
            const int4* p4 = (const int4*)S.cc;
            for (int ch = 0; ch < 49; ++ch) {
                int4 c0 = p4[ch * 4 + 0];
                int4 c1 = p4[ch * 4 + 1];
                int4 c2 = p4[ch * 4 + 2];
                int4 c3 = p4[ch * 4 + 3];
                int c[16] = {c0.x, c0.y, c0.z, c0.w, c1.x, c1.y, c1.z, c1.w,
                             c2.x, c2.y, c2.z, c2.w, c3.x, c3.y, c3.z, c3.w};
#pragma unroll
                for (int u2 = 0; u2 < 16; ++u2) {
                    int t = ch * 16 + u2;
                    rA += (c[u2] > vA) || (c[u2] == vA && t < sA);
                    rB += (c[u2] > vB) || (c[u2] == vB && t < sB);
                }
            }
            if (rA < select_num && rA < 64) S.found[rA] = sA + 1;     // +1: patch_idx offset
            if (sB >= 0 && rB < select_num && rB < 64) S.found[rB] = sB + 1;
            __syncthreads();

            int totalT = select_num * (Dd / 4);
            for (int t = tid; t < totalT; t += 256) {
                int r = t / (Dd / 4);
                int d = t - r * (Dd / 4);
                int src = S.found[r];
                if (src < 0) continue;                       // other half owns rank r
                const float4* sp = (const float4*)(hs + ((size_t)b * Nn + src) * Dd);
                float4* dp = (float4*)(out + (size_t)Bz * Nn * Dd + ((size_t)b * select_num + r) * Dd);
                dp[d] = sp[d];
            }
        }
    }
}

// ---------------- Node 2: pure copy of rows 1..784 ----------------
__global__ __launch_bounds__(256) void kCopy(const float* __restrict__ hs,
                                             float* __restrict__ out) {
    const unsigned perB   = (unsigned)(Ss * Dd / 4);     // 150,528
    const unsigned rowPit = (unsigned)(Nn * Dd / 4);     // 150,720
    unsigned f = blockIdx.x * 256u + threadIdx.x;        // < 1,204,224 exactly
    unsigned b = f / perB;
    unsigned r = f - b * perB;
    unsigned idx = b * rowPit + (unsigned)(Dd / 4) + r;  // skip row 0
    ((float4*)out)[idx] = ((const float4*)hs)[idx];
}

extern "C" void kernel_launch(void* const* d_in, const int* in_sizes, int n_in,
                              void* d_out, int out_size, void* d_ws, size_t ws_size,
                              hipStream_t stream) {
    const float* hs = (const float*)d_in[0];
    const float* x  = (const float*)d_in[1];
    const float* w1 = (const float*)d_in[2];
    const float* w2 = (const float*)d_in[3];
    float* out = (float*)d_out;

    const int hsN = Bz * Nn * Dd;                       // 4,823,040
    int select_num = (out_size - hsN) / (Bz * Dd);      // = 42

    // workspace carve (bytes)
    char* ws = (char*)d_ws;
    float* nscore = (float*)ws;                                   // 96*784*4 = 301056 B
    unsigned char* flags = (unsigned char*)(ws + 301056);         // 96*784   =  75264 B
    unsigned long long* ready = (unsigned long long*)(ws + 376320); // 96*8   =    768 B

    kNode1<<<NNODE1, 256, 0, stream>>>(hs, x, w1, w2, nscore, flags, ready, out, select_num);
    kCopy<<<NCPY, 256, 0, stream>>>(hs, out);
}

// Round 11
// 62.330 us; speedup vs baseline: 2.2371x; 2.2371x over previous
//
#include <hip/hip_runtime.h>
#include <math.h>

#define Bz 8
#define Cc 12
#define Ss 784
#define Nn 785
#define Dd 768
#define Hh 28
#define K1 512
#define PATCHNUM 84

#define NTOPK 384                 // 8b * 12c * 4 quarters
#define NG1 96                    // 8b * 12 colblocks
#define NG2 16                    // 8b * 2 halves
#define CPY0 (NTOPK + NG1 + NG2)  // 496
#define NBLK 2048
#define NCPYB (NBLK - CPY0)       // 1552

#define MAGIC 0x5EC7ED42C0FFEE01ULL

// ---- SYSTEM-scope (sc0 sc1) accessors: bypass L1 + local L2, hit the coherent point.
// No fences anywhere: producer __syncthreads() drains vmcnt(0) (stores complete at
// system scope), consumer sc1 loads can't see stale lines.
__device__ inline float ld_sys_f(const float* p) {
    return __hip_atomic_load(p, __ATOMIC_RELAXED, __HIP_MEMORY_SCOPE_SYSTEM);
}
__device__ inline void st_sys_f(float* p, float v) {
    __hip_atomic_store(p, v, __ATOMIC_RELAXED, __HIP_MEMORY_SCOPE_SYSTEM);
}
__device__ inline int ld_sys_i(const int* p) {
    return __hip_atomic_load(p, __ATOMIC_RELAXED, __HIP_MEMORY_SCOPE_SYSTEM);
}
__device__ inline void st_sys_i(int* p, int v) {
    __hip_atomic_store(p, v, __ATOMIC_RELAXED, __HIP_MEMORY_SCOPE_SYSTEM);
}
__device__ inline unsigned long long ld_sys_u64(const unsigned long long* p) {
    return __hip_atomic_load(p, __ATOMIC_RELAXED, __HIP_MEMORY_SCOPE_SYSTEM);
}

__device__ inline float waveSum(float v) {
#pragma unroll
    for (int off = 32; off > 0; off >>= 1) v += __shfl_xor(v, off);
    return v;
}

struct GT { float sc[Ss]; };
struct G1 {
    float m[Ss];
    float pw[Ss];
    float g[K1];
    float part[4][64];
    float w4[4][4];
    float av[4];
    int   ai4[4];
};
struct G2 {
    int cnt[Ss];
    int cc[Ss];
    int found[64];
};
union SMem { GT gt; G1 g1; G2 g2; };

__global__ __launch_bounds__(256) void kOne(const float* __restrict__ hs,
                                            const float* __restrict__ x,
                                            const float* __restrict__ w1,
                                            const float* __restrict__ w2,
                                            float* __restrict__ nscore,
                                            int* __restrict__ flagsI,
                                            unsigned long long* __restrict__ ready,
                                            float* __restrict__ out,
                                            int select_num) {
    __shared__ SMem sm;
    int bid = blockIdx.x;
    int tid = threadIdx.x;
    int lane = tid & 63, wid = tid >> 6;

    if (bid < NTOPK) {
        // ======== producers: per (b,c,quarter) top-84 rank -> nscore, flagsI (sc1 stores) ========
        int bc = bid >> 2;
        int quarter = bid & 3;
        const float* sc = x + (size_t)bc * Nn * Nn + 1;   // x[b,c,0,1:]
        float* s_sc = sm.gt.sc;
        for (int s = tid; s < Ss; s += 256) s_sc[s] = sc[s];
        __syncthreads();

        int s = tid + 256 * quarter;
        bool valid = (s < Ss);
        float v = valid ? s_sc[s] : 0.f;
        int rank = 0;
        const float4* s4 = (const float4*)s_sc;
        for (int chunk = 0; chunk < Ss / 16; ++chunk) {   // 49 chunks of 16
            float4 c0 = s4[chunk * 4 + 0];
            float4 c1 = s4[chunk * 4 + 1];
            float4 c2 = s4[chunk * 4 + 2];
            float4 c3 = s4[chunk * 4 + 3];
            float c[16] = {c0.x, c0.y, c0.z, c0.w, c1.x, c1.y, c1.z, c1.w,
                           c2.x, c2.y, c2.z, c2.w, c3.x, c3.y, c3.z, c3.w};
#pragma unroll
            for (int u = 0; u < 16; ++u) {
                int t = chunk * 16 + u;
                rank += (c[u] > v) || (c[u] == v && t < s);
            }
        }
        if (valid) {
            bool sel = rank < PATCHNUM;               // lax.top_k tie-break: lower index
            st_sys_i(&flagsI[(size_t)bc * Ss + s], sel ? 1 : 0);
            st_sys_f(&nscore[(size_t)bc * Ss + s], sel ? v : v * 0.7f);
        }
        __syncthreads();                              // vmcnt(0): sc1 stores complete at MALL
        if (tid == 0)
            atomicExch(&ready[bid], (unsigned long long)MAGIC);   // idempotent across replays
    } else if (bid < CPY0) {
        // ======== consumers: poll my b's 48 producer flags with sc1 loads (no RMW, no fence) ========
        int b;
        if (bid < NTOPK + NG1) b = (bid - NTOPK) / 12;
        else                   b = (bid - NTOPK - NG1) >> 1;

        if (tid < 48) {
            while (ld_sys_u64(&ready[b * 48 + tid]) != MAGIC)
                __builtin_amdgcn_s_sleep(32);         // ~0.85us backoff per retry
        }
        __syncthreads();

        if (bid < NTOPK + NG1) {
            // ---- group 1: per-b stats + 64-col slice of o2; write out row 0 ----
            G1& S = sm.g1;
            int colblk = (bid - NTOPK) % 12;

            // phase 1: m, pw, sum(m), P2p, P2n (nscore via sc1 loads)
            const float* ns = nscore + (size_t)b * Cc * Ss;
            float lsum = 0.f, lp = 0.f, ln2 = 0.f;
            for (int s = tid; s < Ss; s += 256) {
                float m = 0.f;
#pragma unroll
                for (int c = 0; c < Cc; ++c) m += ld_sys_f(&ns[c * Ss + s]);
                S.m[s] = m;
                float pw = m / 12.0f;
                S.pw[s] = pw;
                lsum += m;
                if (pw > 0.f) lp += pw * pw;
                else if (pw < 0.f) ln2 += pw * pw;
            }
            lsum = waveSum(lsum); lp = waveSum(lp); ln2 = waveSum(ln2);
            if (lane == 0) {
                S.w4[wid][0] = lsum; S.w4[wid][1] = lp; S.w4[wid][2] = ln2;
            }
            __syncthreads();
            float meanm = (S.w4[0][0] + S.w4[1][0] + S.w4[2][0] + S.w4[3][0]) / 784.0f;
            float P2p   =  S.w4[0][1] + S.w4[1][1] + S.w4[2][1] + S.w4[3][1];
            float P2n   =  S.w4[0][2] + S.w4[1][2] + S.w4[2][2] + S.w4[3][2];

            // phase 2: anchor = argmax_s ((m>mean) ? pw : 0), first max wins
            float bv = -INFINITY; int bi = Ss;
            for (int s = tid; s < Ss; s += 256) {
                float z = (S.m[s] > meanm) ? S.pw[s] : 0.0f;
                if (z > bv) { bv = z; bi = s; }
            }
#pragma unroll
            for (int off = 32; off > 0; off >>= 1) {
                float ov = __shfl_xor(bv, off);
                int   oi = __shfl_xor(bi, off);
                if (ov > bv || (ov == bv && oi < bi)) { bv = ov; bi = oi; }
            }
            if (lane == 0) { S.av[wid] = bv; S.ai4[wid] = bi; }
            __syncthreads();
            float abv = S.av[0]; int anchor = S.ai4[0];
#pragma unroll
            for (int w = 1; w < 4; ++w) {
                if (S.av[w] > abv || (S.av[w] == abv && S.ai4[w] < anchor)) {
                    abv = S.av[w]; anchor = S.ai4[w];
                }
            }

            // phase 3: A, G (depend on anchor)
            int ai = anchor / Hh, aj = anchor % Hh;
            float lA = 0.f, lG = 0.f;
            const float PI_F = 3.14159265358979323846f;
            for (int s = tid; s < Ss; s += 256) {
                float pw = S.pw[s];
                int i = s / Hh, j = s % Hh;
                float ri = (float)(i - ai) / 28.0f;
                float rj = (float)(j - aj) / 28.0f;
                float dist = sqrtf(ri * ri + rj * rj);
                float ang = (atan2f(rj, ri) / PI_F + 1.0f) * 0.5f;
                lA += pw * dist;
                lG += pw * ang;
            }
            lA = waveSum(lA); lG = waveSum(lG);
            __syncthreads();
            if (lane == 0) { S.w4[wid][0] = lA; S.w4[wid][1] = lG; }
            __syncthreads();
            float A = S.w4[0][0] + S.w4[1][0] + S.w4[2][0] + S.w4[3][0];
            float G = S.w4[0][1] + S.w4[1][1] + S.w4[2][1] + S.w4[3][1];
            float pwA = S.pw[anchor];
            float cp = pwA * P2p, cn = pwA * P2n;

            // phase 4: g[k]  (w1 is a read-only input: normal cached loads)
            for (int k = tid; k < K1; k += 256) {
                float v = A * w1[k] + G * w1[K1 + k];
                S.g[k] = cp * fmaxf(v, 0.f) - cn * fmaxf(-v, 0.f);
            }
            __syncthreads();

            // phase 5: matvec 64 cols x 512 k (4 k-chunks across warps)
            int col = colblk * 64 + lane;
            int kc = wid;                          // 0..3, 128 k each
            float acc = 0.f;
            const float* w2p = w2 + (size_t)(kc * 128) * Dd + col;
#pragma unroll 8
            for (int kk = 0; kk < 128; ++kk)
                acc += S.g[kc * 128 + kk] * w2p[kk * Dd];
            S.part[kc][lane] = acc;
            __syncthreads();
            if (tid < 64) {
                float o2 = S.part[0][tid] + S.part[1][tid] + S.part[2][tid] + S.part[3][tid];
                float r = (o2 > 0.f) ? o2 : 0.2f * o2;
                size_t off = (size_t)b * Nn * Dd + colblk * 64 + tid;   // row 0
                out[off] = hs[off] + r;
            }
        } else {
            // ---- group 2: count (sc1 flag loads) -> conv -> stable rank -> gather rows ----
            G2& S = sm.g2;
            int half = (bid - NTOPK - NG1) & 1;

            for (int r = tid; r < 64; r += 256) S.found[r] = -1;
            for (int s = tid; s < Ss; s += 256) {
                int c0 = 0;
#pragma unroll
                for (int c = 0; c < Cc; ++c) c0 += ld_sys_i(&flagsI[((size_t)b * Cc + c) * Ss + s]);
                S.cnt[s] = c0;
            }
            __syncthreads();
            for (int s = tid; s < Ss; s += 256) {
                int i = s / Hh, j = s % Hh;
                int acc = 0;
                for (int di = -1; di <= 1; ++di)
                    for (int dj = -1; dj <= 1; ++dj) {
                        int ii = i + di, jj = j + dj;
                        if (ii >= 0 && ii < Hh && jj >= 0 && jj < Hh)
                            acc += ((di == 0) ? 2 : 1) * ((dj == 0) ? 2 : 1) * S.cnt[ii * Hh + jj];
                    }
                S.cc[s] = acc;
            }
            __syncthreads();

            int sA = half * 392 + tid;                       // [h*392, h*392+256)
            int sB = (tid < 136) ? (half * 392 + 256 + tid) : -1;
            int vA = S.cc[sA];
            int vB = (sB >= 0) ? S.cc[sB] : 0;
            int rA = 0, rB = 0;
            const int4* p4 = (const int4*)S.cc;
            for (int ch = 0; ch < 49; ++ch) {
                int4 c0 = p4[ch * 4 + 0];
                int4 c1 = p4[ch * 4 + 1];
                int4 c2 = p4[ch * 4 + 2];
                int4 c3 = p4[ch * 4 + 3];
                int c[16] = {c0.x, c0.y, c0.z, c0.w, c1.x, c1.y, c1.z, c1.w,
                             c2.x, c2.y, c2.z, c2.w, c3.x, c3.y, c3.z, c3.w};
#pragma unroll
                for (int u2 = 0; u2 < 16; ++u2) {
                    int t = ch * 16 + u2;
                    rA += (c[u2] > vA) || (c[u2] == vA && t < sA);
                    rB += (c[u2] > vB) || (c[u2] == vB && t < sB);
                }
            }
            if (rA < select_num && rA < 64) S.found[rA] = sA + 1;     // +1: patch_idx offset
            if (sB >= 0 && rB < select_num && rB < 64) S.found[rB] = sB + 1;
            __syncthreads();

            int totalT = select_num * (Dd / 4);
            for (int t = tid; t < totalT; t += 256) {
                int r = t / (Dd / 4);
                int d = t - r * (Dd / 4);
                int src = S.found[r];
                if (src < 0) continue;                       // other half owns rank r
                const float4* sp = (const float4*)(hs + ((size_t)b * Nn + src) * Dd);
                float4* dp = (float4*)(out + (size_t)Bz * Nn * Dd + ((size_t)b * select_num + r) * Dd);
                dp[d] = sp[d];
            }
        }
    } else {
        // ======== copy blocks: rows 1..784, grid-stride, no sync, normal cached path ========
        const unsigned perB   = (unsigned)(Ss * Dd / 4);     // 150,528
        const unsigned rowPit = (unsigned)(Nn * Dd / 4);     // 150,720
        const unsigned totalF4 = (unsigned)Bz * perB;        // 1,204,224
        const float4* src = (const float4*)hs;
        float4* dst = (float4*)out;
        unsigned f = (unsigned)(bid - CPY0) * 256u + (unsigned)tid;
        for (; f < totalF4; f += (unsigned)NCPYB * 256u) {
            unsigned b = f / perB;
            unsigned r = f - b * perB;
            unsigned idx = b * rowPit + (unsigned)(Dd / 4) + r;  // skip row 0
            dst[idx] = src[idx];
        }
    }
}

extern "C" void kernel_launch(void* const* d_in, const int* in_sizes, int n_in,
                              void* d_out, int out_size, void* d_ws, size_t ws_size,
                              hipStream_t stream) {
    const float* hs = (const float*)d_in[0];
    const float* x  = (const float*)d_in[1];
    const float* w1 = (const float*)d_in[2];
    const float* w2 = (const float*)d_in[3];
    float* out = (float*)d_out;

    const int hsN = Bz * Nn * Dd;                       // 4,823,040
    int select_num = (out_size - hsN) / (Bz * Dd);      // = 42

    // workspace carve (bytes)
    char* ws = (char*)d_ws;
    float* nscore = (float*)ws;                                     // 96*784*4 = 301056 B
    int* flagsI   = (int*)(ws + 301056);                            // 96*784*4 = 301056 B
    unsigned long long* ready = (unsigned long long*)(ws + 602112); // 384*8    =   3072 B

    kOne<<<NBLK, 256, 0, stream>>>(hs, x, w1, w2, nscore, flagsI, ready, out, select_num);
}